// Round 4
// baseline (160.988 us; speedup 1.0000x reference)
//
#include <hip/hip_runtime.h>

#define N2 4096
#define D 128
#define TAU_INV 10.0f
#define JSL 16                    // j-slices per i-tile row; grid = 128 * JSL
#define TPW (N2 / (JSL * 128))    // j-tiles per wave = 2

typedef __attribute__((ext_vector_type(8))) short bf16x8;
typedef __attribute__((ext_vector_type(16))) float floatx16;

__device__ __forceinline__ short f2bf(float f) {
    unsigned u = __float_as_uint(f);
    u = (u + 0x7fff + ((u >> 16) & 1)) >> 16;   // RNE
    return (short)u;
}
__device__ __forceinline__ float bf2f(short s) {
    return __uint_as_float(((unsigned)(unsigned short)s) << 16);
}

// Normalize rows of p = concat(z_i, z_j) in fp32, emit bf16 Q.
// Also accumulate per-class: S_c (vector sum of q), T_c (sum of ||q||^2), CNT_c.
// These give the positive-pair term without any O(N^2) work:
//   sum_i sp_i/cnt_i = sum_c 10*(||S_c||^2 - T_c)/(n_c - 1)
// SAFETY: c is the only data-dependent index in the whole pipeline; guard it
// so a launch on poisoned inputs can never fault (round-0 property).
__global__ __launch_bounds__(64) void prep_kernel(const float* __restrict__ zi,
                                                  const float* __restrict__ zj,
                                                  const long long* __restrict__ y,
                                                  short* __restrict__ qb,
                                                  float* __restrict__ S,
                                                  float* __restrict__ T,
                                                  float* __restrict__ CNT) {
    int row = blockIdx.x;
    int lane = threadIdx.x;                    // 64 lanes, 2 floats each
    const float* src = (row < 2048) ? (zi + row * D) : (zj + (row - 2048) * D);
    float2 v = ((const float2*)src)[lane];
    float ss = v.x * v.x + v.y * v.y;
    #pragma unroll
    for (int m = 1; m < 64; m <<= 1) ss += __shfl_xor(ss, m);
    float inv = 1.0f / sqrtf(ss);              // ||p|| ~ sqrt(128) >> eps
    short2 o;
    o.x = f2bf(v.x * inv);
    o.y = f2bf(v.y * inv);
    ((short2*)(qb + row * D))[lane] = o;

    // class accumulators use the dequantized bf16 values (match MFMA inputs)
    float qx = bf2f(o.x), qy = bf2f(o.y);
    float sd = qx * qx + qy * qy;
    #pragma unroll
    for (int m = 1; m < 64; m <<= 1) sd += __shfl_xor(sd, m);
    int c = (int)y[row & 2047];
    if ((unsigned)c < 10u) {                   // guard: no data-dependent OOB
        atomicAdd(&S[c * D + 2 * lane],     qx);
        atomicAdd(&S[c * D + 2 * lane + 1], qy);
        if (lane == 0) { atomicAdd(&T[c], sd); atomicAdd(&CNT[c], 1.0f); }
    }
}

// Each block: one 32-row i-tile x one 256-col j-slice. 4 waves; wave w does
// j-tiles w, w+4 (32 cols each). MFMA 32x32x16 bf16, K=128 (8 steps).
// A/B frags: lane holds row base+(lane&31), 8 contiguous bf16 at k*16+(lane>>5)*8.
// C/D: col = lane&31, row = (reg&3) + 8*(reg>>2) + 4*(lane>>5).
// Only accumulates se (exp-sum, diagonal excluded). Diagonal occurs only in the
// tile with j0 == i0 (wave-uniform branch), so se is bit-identical to before.
__global__ __launch_bounds__(256) void main_kernel(const short* __restrict__ qb,
                                                   float* __restrict__ se_g) {
    int tid = threadIdx.x;
    int wave = tid >> 6;
    int lane = tid & 63;
    int col  = lane & 31;
    int half = lane >> 5;
    int it = blockIdx.x >> 4;          // 0..127
    int js = blockIdx.x & (JSL - 1);   // 0..15
    int i0 = it * 32;
    int jbase = js * (N2 / JSL);

    // A fragments for this block's 32 i-rows (reused across all j-tiles)
    const short* ap = qb + (i0 + col) * D + half * 8;
    bf16x8 af[8];
    #pragma unroll
    for (int k = 0; k < 8; ++k) af[k] = *(const bf16x8*)(ap + k * 16);

    float se[16];
    #pragma unroll
    for (int r = 0; r < 16; ++r) se[r] = 0.f;

    #pragma unroll
    for (int t = 0; t < TPW; ++t) {
        int j0 = jbase + (wave + 4 * t) * 32;
        const short* bp = qb + (j0 + col) * D + half * 8;
        bf16x8 bf[8];
        #pragma unroll
        for (int k = 0; k < 8; ++k) bf[k] = *(const bf16x8*)(bp + k * 16);

        floatx16 acc;
        #pragma unroll
        for (int r = 0; r < 16; ++r) acc[r] = 0.f;
        #pragma unroll
        for (int k = 0; k < 8; ++k)
            acc = __builtin_amdgcn_mfma_f32_32x32x16_bf16(af[k], bf[k], acc, 0, 0, 0);

        if (j0 == i0) {                       // wave-uniform: diagonal tile
            int jcol = j0 + col;
            #pragma unroll
            for (int r = 0; r < 16; ++r) {
                int rowr = i0 + (r & 3) + 8 * (r >> 2) + 4 * half;
                float e = __expf(acc[r] * TAU_INV);
                se[r] += (rowr == jcol) ? 0.f : e;
            }
        } else {
            #pragma unroll
            for (int r = 0; r < 16; ++r)
                se[r] += __expf(acc[r] * TAU_INV);
        }
    }

    // reduce across the 32 cols (stay within each 32-lane half) and accumulate
    #pragma unroll
    for (int r = 0; r < 16; ++r) {
        float a = se[r];
        #pragma unroll
        for (int m = 1; m < 32; m <<= 1) a += __shfl_xor(a, m);
        if (col == 0) {
            int rowr = i0 + (r & 3) + 8 * (r >> 2) + 4 * half;
            atomicAdd(&se_g[rowr], a);
        }
    }
}

// loss = (sum_i log se_i  -  sum_c 10*(||S_c||^2 - T_c)/(n_c-1)) / N2
__global__ __launch_bounds__(256) void finish_kernel(const float* __restrict__ se_g,
                                                     const float* __restrict__ S,
                                                     const float* __restrict__ T,
                                                     const float* __restrict__ CNT,
                                                     float* __restrict__ out) {
    int tid = threadIdx.x;
    int wave = tid >> 6;
    int lane = tid & 63;

    // positive-pair term: wave w handles classes w, w+4, w+8
    float P = 0.f;
    for (int c = wave; c < 10; c += 4) {
        float2 sv = ((const float2*)(S + c * D))[lane];
        float s2 = sv.x * sv.x + sv.y * sv.y;
        #pragma unroll
        for (int m = 1; m < 64; m <<= 1) s2 += __shfl_xor(s2, m);
        float n = CNT[c];
        P += (n >= 2.0f) ? (s2 - T[c]) * TAU_INV / (n - 1.0f) : 0.f;
    }

    // denominator term
    float L = 0.f;
    for (int i = tid; i < N2; i += 256) L += __logf(se_g[i]);
    #pragma unroll
    for (int m = 1; m < 64; m <<= 1) L += __shfl_xor(L, m);

    __shared__ float red[8];
    if (lane == 0) { red[wave] = L; red[4 + wave] = P; }
    __syncthreads();
    if (tid == 0) {
        float Ls = red[0] + red[1] + red[2] + red[3];
        float Ps = red[4] + red[5] + red[6] + red[7];
        out[0] = (Ls - Ps) * (1.0f / (float)N2);
    }
}

extern "C" void kernel_launch(void* const* d_in, const int* in_sizes, int n_in,
                              void* d_out, int out_size, void* d_ws, size_t ws_size,
                              hipStream_t stream) {
    const float*     zi = (const float*)d_in[0];
    const float*     zj = (const float*)d_in[1];
    const long long* y  = (const long long*)d_in[2];
    float* out = (float*)d_out;

    char* ws = (char*)d_ws;
    short* qb   = (short*)ws;                               // 4096*128*2B = 1 MB
    float* se_g = (float*)(ws + N2 * D * sizeof(short));    // 16 KB
    float* S    = se_g + N2;                                // 10*128 f32 = 5120 B
    float* T    = S + 10 * D;                               // 40 B
    float* CNT  = T + 10;                                   // 40 B

    // zero se_g + S + T + CNT in one contiguous memset
    hipMemsetAsync(se_g, 0, (N2 + 10 * D + 10 + 10) * sizeof(float), stream);
    prep_kernel<<<N2, 64, 0, stream>>>(zi, zj, y, qb, S, T, CNT);
    main_kernel<<<128 * JSL, 256, 0, stream>>>(qb, se_g);
    finish_kernel<<<1, 256, 0, stream>>>(se_g, S, T, CNT, out);
}

// Round 5
// 137.940 us; speedup vs baseline: 1.1671x; 1.1671x over previous
//
#include <hip/hip_runtime.h>

#define N2 4096
#define D 128
#define TAU_INV 10.0f
#define JSL 8                     // j-slices per i-tile row; grid = 128 * JSL
#define TPW (N2 / (JSL * 128))    // j-tiles per wave = 4
#define PBLK 128                  // prep blocks
#define RPB (N2 / PBLK)           // 32 rows per prep block
#define NCLS 10
#define PSZ (NCLS * D + 2 * NCLS) // 1300 floats per block partial: S[10][128], T[10], CNT[10]

typedef __attribute__((ext_vector_type(8))) short bf16x8;
typedef __attribute__((ext_vector_type(16))) float floatx16;

__device__ __forceinline__ short f2bf(float f) {
    unsigned u = __float_as_uint(f);
    u = (u + 0x7fff + ((u >> 16) & 1)) >> 16;   // RNE
    return (short)u;
}
__device__ __forceinline__ float bf2f(short s) {
    return __uint_as_float(((unsigned)(unsigned short)s) << 16);
}

// Normalize rows of p = concat(z_i, z_j) in fp32, emit bf16 Q.
// Class sums S_c/T_c/CNT_c accumulate in LDS (no global atomics!), one
// 1300-float partial per block; finish reduces the 128 partials.
// Positive-pair term: sum_i sp_i/cnt_i = sum_c 10*(||S_c||^2 - T_c)/(n_c-1).
// Also zeroes this block's slice of se_g (replaces the memset dispatch).
__global__ __launch_bounds__(256) void prep_kernel(const float* __restrict__ zi,
                                                   const float* __restrict__ zj,
                                                   const long long* __restrict__ y,
                                                   short* __restrict__ qb,
                                                   float* __restrict__ partial,
                                                   float* __restrict__ se_g) {
    __shared__ float sh[PSZ];
    int tid = threadIdx.x;
    int b = blockIdx.x;
    for (int k = tid; k < PSZ; k += 256) sh[k] = 0.f;
    if (tid < RPB) se_g[b * RPB + tid] = 0.f;
    __syncthreads();

    int wave = tid >> 6, lane = tid & 63;
    #pragma unroll
    for (int i = 0; i < RPB / 4; ++i) {                 // 8 rows per wave
        int row = b * RPB + wave * (RPB / 4) + i;
        const float* src = (row < 2048) ? (zi + row * D) : (zj + (row - 2048) * D);
        float2 v = ((const float2*)src)[lane];
        float ss = v.x * v.x + v.y * v.y;
        #pragma unroll
        for (int m = 1; m < 64; m <<= 1) ss += __shfl_xor(ss, m);
        float inv = 1.0f / sqrtf(ss);                   // ||p|| ~ sqrt(128) >> eps
        short2 o;
        o.x = f2bf(v.x * inv);
        o.y = f2bf(v.y * inv);
        ((short2*)(qb + row * D))[lane] = o;

        // class accumulators use dequantized bf16 values (match MFMA inputs)
        float qx = bf2f(o.x), qy = bf2f(o.y);
        float sd = qx * qx + qy * qy;
        #pragma unroll
        for (int m = 1; m < 64; m <<= 1) sd += __shfl_xor(sd, m);
        int c = (int)y[row & 2047];
        if ((unsigned)c < (unsigned)NCLS) {             // no data-dependent OOB
            atomicAdd(&sh[c * D + 2 * lane],     qx);   // LDS atomics, banks spread
            atomicAdd(&sh[c * D + 2 * lane + 1], qy);
            if (lane == 0) {
                atomicAdd(&sh[NCLS * D + c], sd);
                atomicAdd(&sh[NCLS * D + NCLS + c], 1.0f);
            }
        }
    }
    __syncthreads();
    for (int k = tid; k < PSZ; k += 256) partial[b * PSZ + k] = sh[k];
}

// Each block: one 32-row i-tile x one 512-col j-slice. 4 waves; wave w does
// j-tiles w, w+4, w+8, w+12 (32 cols each). MFMA 32x32x16 bf16, K=128 (8 steps).
// A/B frags: lane holds row base+(lane&31), 8 contiguous bf16 at k*16+(lane>>5)*8.
// C/D: col = lane&31, row = (reg&3) + 8*(reg>>2) + 4*(lane>>5).
// Only accumulates se (exp-sum, diagonal excluded). Diagonal occurs only in the
// tile with j0 == i0 (wave-uniform branch).
__global__ __launch_bounds__(256) void main_kernel(const short* __restrict__ qb,
                                                   float* __restrict__ se_g) {
    int tid = threadIdx.x;
    int wave = tid >> 6;
    int lane = tid & 63;
    int col  = lane & 31;
    int half = lane >> 5;
    int it = blockIdx.x >> 3;          // 0..127
    int js = blockIdx.x & (JSL - 1);   // 0..7
    int i0 = it * 32;
    int jbase = js * (N2 / JSL);

    // A fragments for this block's 32 i-rows (reused across all j-tiles)
    const short* ap = qb + (i0 + col) * D + half * 8;
    bf16x8 af[8];
    #pragma unroll
    for (int k = 0; k < 8; ++k) af[k] = *(const bf16x8*)(ap + k * 16);

    float se[16];
    #pragma unroll
    for (int r = 0; r < 16; ++r) se[r] = 0.f;

    #pragma unroll
    for (int t = 0; t < TPW; ++t) {
        int j0 = jbase + (wave + 4 * t) * 32;
        const short* bp = qb + (j0 + col) * D + half * 8;
        bf16x8 bf[8];
        #pragma unroll
        for (int k = 0; k < 8; ++k) bf[k] = *(const bf16x8*)(bp + k * 16);

        floatx16 acc;
        #pragma unroll
        for (int r = 0; r < 16; ++r) acc[r] = 0.f;
        #pragma unroll
        for (int k = 0; k < 8; ++k)
            acc = __builtin_amdgcn_mfma_f32_32x32x16_bf16(af[k], bf[k], acc, 0, 0, 0);

        if (j0 == i0) {                       // wave-uniform: diagonal tile
            int jcol = j0 + col;
            #pragma unroll
            for (int r = 0; r < 16; ++r) {
                int rowr = i0 + (r & 3) + 8 * (r >> 2) + 4 * half;
                float e = __expf(acc[r] * TAU_INV);
                se[r] += (rowr == jcol) ? 0.f : e;
            }
        } else {
            #pragma unroll
            for (int r = 0; r < 16; ++r)
                se[r] += __expf(acc[r] * TAU_INV);
        }
    }

    // reduce across the 32 cols (stay within each 32-lane half) and accumulate
    #pragma unroll
    for (int r = 0; r < 16; ++r) {
        float a = se[r];
        #pragma unroll
        for (int m = 1; m < 32; m <<= 1) a += __shfl_xor(a, m);
        if (col == 0) {
            int rowr = i0 + (r & 3) + 8 * (r >> 2) + 4 * half;
            atomicAdd(&se_g[rowr], a);
        }
    }
}

// loss = (sum_i log se_i  -  sum_c 10*(||S_c||^2 - T_c)/(n_c-1)) / N2
__global__ __launch_bounds__(256) void finish_kernel(const float* __restrict__ se_g,
                                                     const float* __restrict__ partial,
                                                     float* __restrict__ out) {
    __shared__ float sh[PSZ];
    __shared__ float red[8];
    int tid = threadIdx.x;

    // reduce the 128 block partials (coalesced across threads for each b)
    for (int k = tid; k < PSZ; k += 256) {
        float s = 0.f;
        for (int bk = 0; bk < PBLK; ++bk) s += partial[bk * PSZ + k];
        sh[k] = s;
    }
    __syncthreads();

    int wave = tid >> 6, lane = tid & 63;

    // positive-pair term: wave w handles classes w, w+4, w+8
    float P = 0.f;
    for (int c = wave; c < NCLS; c += 4) {
        float2 sv = ((const float2*)(sh + c * D))[lane];
        float s2 = sv.x * sv.x + sv.y * sv.y;
        #pragma unroll
        for (int m = 1; m < 64; m <<= 1) s2 += __shfl_xor(s2, m);
        float n = sh[NCLS * D + NCLS + c];
        P += (n >= 2.0f) ? (s2 - sh[NCLS * D + c]) * TAU_INV / (n - 1.0f) : 0.f;
    }

    // denominator term
    float L = 0.f;
    for (int i = tid; i < N2; i += 256) L += __logf(se_g[i]);
    #pragma unroll
    for (int m = 1; m < 64; m <<= 1) L += __shfl_xor(L, m);

    if (lane == 0) { red[wave] = L; red[4 + wave] = P; }
    __syncthreads();
    if (tid == 0) {
        float Ls = red[0] + red[1] + red[2] + red[3];
        float Ps = red[4] + red[5] + red[6] + red[7];
        out[0] = (Ls - Ps) * (1.0f / (float)N2);
    }
}

extern "C" void kernel_launch(void* const* d_in, const int* in_sizes, int n_in,
                              void* d_out, int out_size, void* d_ws, size_t ws_size,
                              hipStream_t stream) {
    const float*     zi = (const float*)d_in[0];
    const float*     zj = (const float*)d_in[1];
    const long long* y  = (const long long*)d_in[2];
    float* out = (float*)d_out;

    char* ws = (char*)d_ws;
    short* qb      = (short*)ws;                             // 4096*128*2B = 1 MB
    float* se_g    = (float*)(ws + N2 * D * sizeof(short));  // 16 KB
    float* partial = se_g + N2;                              // 128*1300*4B = 666 KB

    prep_kernel<<<PBLK, 256, 0, stream>>>(zi, zj, y, qb, partial, se_g);
    main_kernel<<<128 * JSL, 256, 0, stream>>>(qb, se_g);
    finish_kernel<<<1, 256, 0, stream>>>(se_g, partial, out);
}

// Round 6
// 98.549 us; speedup vs baseline: 1.6336x; 1.3997x over previous
//
#include <hip/hip_runtime.h>

#define N2 4096
#define D 128
#define TAU_INV 10.0f
#define JSL 4                     // j-slices per i-tile row
#define TPW (N2 / (JSL * 128))    // j-tiles per wave = 8
#define GEMM_BLOCKS (128 * JSL)   // 512
#define NCLS 10
#define CGRP 16                   // row-groups per class
#define CROWS (N2 / CGRP)         // 256 rows per class block
#define CB (NCLS * CGRP)          // 160 class blocks

typedef __attribute__((ext_vector_type(8))) short bf16x8;
typedef __attribute__((ext_vector_type(16))) float floatx16;

__device__ __forceinline__ short f2bf(float f) {
    unsigned u = __float_as_uint(f);
    u = (u + 0x7fff + ((u >> 16) & 1)) >> 16;   // RNE
    return (short)u;
}
__device__ __forceinline__ float bf2f(short s) {
    return __uint_as_float(((unsigned)(unsigned short)s) << 16);
}

// Normalize rows of p = concat(z_i, z_j) in fp32, emit bf16 Q.
// One row per 64-thread block (round-0 proven shape, ~5us).
// Also zeroes se_g (its own row) and block 0 zeroes S/T/CNT.
__global__ __launch_bounds__(64) void prep_kernel(const float* __restrict__ zi,
                                                  const float* __restrict__ zj,
                                                  short* __restrict__ qb,
                                                  float* __restrict__ se_g,
                                                  float* __restrict__ S) {   // S,T,CNT contiguous: 1300 floats
    int row = blockIdx.x;
    int lane = threadIdx.x;                    // 64 lanes, 2 floats each
    const float* src = (row < 2048) ? (zi + row * D) : (zj + (row - 2048) * D);
    float2 v = ((const float2*)src)[lane];
    float ss = v.x * v.x + v.y * v.y;
    #pragma unroll
    for (int m = 1; m < 64; m <<= 1) ss += __shfl_xor(ss, m);
    float inv = 1.0f / sqrtf(ss);              // ||p|| ~ sqrt(128) >> eps
    short2 o;
    o.x = f2bf(v.x * inv);
    o.y = f2bf(v.y * inv);
    ((short2*)(qb + row * D))[lane] = o;
    if (lane == 0) se_g[row] = 0.f;
    if (row == 0)
        for (int k = lane; k < NCLS * D + 2 * NCLS; k += 64) S[k] = 0.f;
}

// Grid = 512 GEMM blocks + 160 class blocks.
//
// GEMM block: one 32-row i-tile x one 1024-col j-slice. 4 waves; wave w does
// j-tiles w+4t, t=0..7 (32 cols each), with register B-prefetch one tile ahead.
// MFMA 32x32x16 bf16, K=128 (8 steps).
// A/B frags: lane holds row base+(lane&31), 8 contiguous bf16 at k*16+(lane>>5)*8.
// C/D: col = lane&31, row = (reg&3) + 8*(reg>>2) + 4*(lane>>5).
// Accumulates only se (exp-sum, diagonal excluded; diagonal tile is wave-uniform).
//
// Class block cb (class c, row-group g): masked sums over 256 rows of qb:
//   S_c[d] += q[r][d], T_c += q^2, CNT_c += 1   (labels used as VALUES only;
// all addresses are structural -> poison-safe). ~130 global atomics per block.
__global__ __launch_bounds__(256) void main_kernel(const short* __restrict__ qb,
                                                   const long long* __restrict__ y,
                                                   float* __restrict__ se_g,
                                                   float* __restrict__ S) {
    int tid = threadIdx.x;

    if (blockIdx.x >= GEMM_BLOCKS) {
        // ---- class-sum path ----
        int cb = blockIdx.x - GEMM_BLOCKS;   // 0..159
        int c  = cb / CGRP;                  // 0..9
        int g  = cb % CGRP;                  // 0..15
        int d  = tid & 127;
        int rh = tid >> 7;                   // 0/1
        int r0 = g * CROWS + rh * (CROWS / 2);

        float sS = 0.f, sT = 0.f, cnt = 0.f;
        #pragma unroll 4
        for (int i = 0; i < CROWS / 2; ++i) {
            int r = r0 + i;
            bool m = ((int)y[r & 2047] == c);      // wave-uniform broadcast
            float q = bf2f(qb[r * D + d]);         // coalesced 128B per wave
            sS += m ? q : 0.f;
            sT += m ? q * q : 0.f;
            cnt += m ? 1.f : 0.f;
        }

        __shared__ float shS[256];
        __shared__ float shT[4];
        __shared__ float shC[2];
        shS[tid] = sS;
        // wave-reduce sT (64-wide)
        #pragma unroll
        for (int m = 1; m < 64; m <<= 1) sT += __shfl_xor(sT, m);
        if ((tid & 63) == 0) shT[tid >> 6] = sT;
        if (d == 0) shC[rh] = cnt;
        __syncthreads();
        if (tid < 128) atomicAdd(&S[c * D + tid], shS[tid] + shS[tid + 128]);
        if (tid == 0) {
            atomicAdd(&S[NCLS * D + c], shT[0] + shT[1] + shT[2] + shT[3]);   // T_c
            atomicAdd(&S[NCLS * D + NCLS + c], shC[0] + shC[1]);              // CNT_c
        }
        return;
    }

    // ---- GEMM path ----
    int wave = tid >> 6;
    int lane = tid & 63;
    int col  = lane & 31;
    int half = lane >> 5;
    int it = blockIdx.x >> 2;          // 0..127
    int js = blockIdx.x & (JSL - 1);   // 0..3
    int i0 = it * 32;
    int jbase = js * (N2 / JSL);

    // A fragments for this block's 32 i-rows (reused across all 8 j-tiles)
    const short* ap = qb + (i0 + col) * D + half * 8;
    bf16x8 af[8];
    #pragma unroll
    for (int k = 0; k < 8; ++k) af[k] = *(const bf16x8*)(ap + k * 16);

    float se[16];
    #pragma unroll
    for (int r = 0; r < 16; ++r) se[r] = 0.f;

    // prefetch B for tile t=0
    bf16x8 bf[8];
    {
        const short* bp = qb + (jbase + wave * 32 + col) * D + half * 8;
        #pragma unroll
        for (int k = 0; k < 8; ++k) bf[k] = *(const bf16x8*)(bp + k * 16);
    }

    #pragma unroll
    for (int t = 0; t < TPW; ++t) {
        int j0 = jbase + (wave + 4 * t) * 32;

        // issue next tile's B loads before the MFMA chain (latency hiding)
        bf16x8 bn[8];
        if (t < TPW - 1) {
            const short* bp = qb + (j0 + 128 + col) * D + half * 8;
            #pragma unroll
            for (int k = 0; k < 8; ++k) bn[k] = *(const bf16x8*)(bp + k * 16);
        }

        floatx16 acc;
        #pragma unroll
        for (int r = 0; r < 16; ++r) acc[r] = 0.f;
        #pragma unroll
        for (int k = 0; k < 8; ++k)
            acc = __builtin_amdgcn_mfma_f32_32x32x16_bf16(af[k], bf[k], acc, 0, 0, 0);

        if (j0 == i0) {                       // wave-uniform: diagonal tile
            int jcol = j0 + col;
            #pragma unroll
            for (int r = 0; r < 16; ++r) {
                int rowr = i0 + (r & 3) + 8 * (r >> 2) + 4 * half;
                float e = __expf(acc[r] * TAU_INV);
                se[r] += (rowr == jcol) ? 0.f : e;
            }
        } else {
            #pragma unroll
            for (int r = 0; r < 16; ++r)
                se[r] += __expf(acc[r] * TAU_INV);
        }

        if (t < TPW - 1) {
            #pragma unroll
            for (int k = 0; k < 8; ++k) bf[k] = bn[k];
        }
    }

    // reduce across the 32 cols (stay within each 32-lane half) and accumulate
    #pragma unroll
    for (int r = 0; r < 16; ++r) {
        float a = se[r];
        #pragma unroll
        for (int m = 1; m < 32; m <<= 1) a += __shfl_xor(a, m);
        if (col == 0) {
            int rowr = i0 + (r & 3) + 8 * (r >> 2) + 4 * half;
            atomicAdd(&se_g[rowr], a);
        }
    }
}

// loss = (sum_i log se_i  -  sum_c 10*(||S_c||^2 - T_c)/(n_c-1)) / N2
__global__ __launch_bounds__(256) void finish_kernel(const float* __restrict__ se_g,
                                                     const float* __restrict__ S,
                                                     float* __restrict__ out) {
    int tid = threadIdx.x;
    int wave = tid >> 6;
    int lane = tid & 63;

    // positive-pair term: wave w handles classes w, w+4, w+8
    float P = 0.f;
    for (int c = wave; c < NCLS; c += 4) {
        float2 sv = ((const float2*)(S + c * D))[lane];
        float s2 = sv.x * sv.x + sv.y * sv.y;
        #pragma unroll
        for (int m = 1; m < 64; m <<= 1) s2 += __shfl_xor(s2, m);
        float n = S[NCLS * D + NCLS + c];
        P += (n >= 2.0f) ? (s2 - S[NCLS * D + c]) * TAU_INV / (n - 1.0f) : 0.f;
    }

    // denominator term
    float L = 0.f;
    for (int i = tid; i < N2; i += 256) L += __logf(se_g[i]);
    #pragma unroll
    for (int m = 1; m < 64; m <<= 1) L += __shfl_xor(L, m);

    __shared__ float red[8];
    if (lane == 0) { red[wave] = L; red[4 + wave] = P; }
    __syncthreads();
    if (tid == 0) {
        float Ls = red[0] + red[1] + red[2] + red[3];
        float Ps = red[4] + red[5] + red[6] + red[7];
        out[0] = (Ls - Ps) * (1.0f / (float)N2);
    }
}

extern "C" void kernel_launch(void* const* d_in, const int* in_sizes, int n_in,
                              void* d_out, int out_size, void* d_ws, size_t ws_size,
                              hipStream_t stream) {
    const float*     zi = (const float*)d_in[0];
    const float*     zj = (const float*)d_in[1];
    const long long* y  = (const long long*)d_in[2];
    float* out = (float*)d_out;

    char* ws = (char*)d_ws;
    short* qb   = (short*)ws;                               // 4096*128*2B = 1 MB
    float* se_g = (float*)(ws + N2 * D * sizeof(short));    // 16 KB
    float* S    = se_g + N2;                                // S[10][128] + T[10] + CNT[10] = 1300 f32

    prep_kernel<<<N2, 64, 0, stream>>>(zi, zj, qb, se_g, S);
    main_kernel<<<GEMM_BLOCKS + CB, 256, 0, stream>>>(qb, y, se_g, S);
    finish_kernel<<<1, 256, 0, stream>>>(se_g, S, out);
}